// Round 10
// baseline (237.556 us; speedup 1.0000x reference)
//
#include <hip/hip_runtime.h>

#define NN 8192
#define TT 60
#define DF 6
#define HH 64
#define GG 256   // 4*H
#define RS 132   // payload width: [0..63] u*last, [64..127] w*last, [128] u, [129] w
#define CH 32    // ranks per chunk/block
#define NB 256   // chunks

typedef _Float16 half8 __attribute__((ext_vector_type(8)));
typedef float f32x4 __attribute__((ext_vector_type(4)));
#define MFMA16(a, b, c) __builtin_amdgcn_mfma_f32_16x16x32_f16((a), (b), (c), 0, 0, 0)

#define LOG2E 1.44269504f

__device__ __forceinline__ float lrelu_(float x) { return x > 0.0f ? x : 0.01f * x; }

// Fused LSTM activations, exp2-domain inputs (R9): gate pre-activations
// arrive ALREADY scaled by -log2e (i,f,o) / -2log2e (g) — folded into the
// f16 weights+biases at load. Saves 16 v_mul/thread/step vs R2-R8 form.
// 5 exp + 3 rcp; clamp only tanh-type args at 63 (saturation exact).
__device__ __forceinline__ float lstm_act2s(float gi, float gf, float gg, float go,
                                            float& c)
{
    const float ei = __builtin_amdgcn_exp2f(gi);
    const float ef = __builtin_amdgcn_exp2f(gf);
    const float eg = __builtin_amdgcn_exp2f(fminf(gg, 63.f));
    const float sf = __builtin_amdgcn_rcpf(1.f + ef);
    const float tg_si = (1.f - eg) * __builtin_amdgcn_rcpf((1.f + ei) * (1.f + eg));
    c = __builtin_fmaf(sf, c, tg_si);
    const float eo = __builtin_amdgcn_exp2f(go);
    const float ec = __builtin_amdgcn_exp2f(fminf(c * (-2.f * LOG2E), 63.f));
    return (1.f - ec) * __builtin_amdgcn_rcpf((1.f + eo) * (1.f + ec));
}

__device__ __forceinline__ half8 ldw8s(const float* __restrict__ p, float s) {
    const float4* q = (const float4*)p;
    float4 u = q[0], v = q[1];
    half8 r;
    r[0]=(_Float16)(u.x*s); r[1]=(_Float16)(u.y*s); r[2]=(_Float16)(u.z*s); r[3]=(_Float16)(u.w*s);
    r[4]=(_Float16)(v.x*s); r[5]=(_Float16)(v.y*s); r[6]=(_Float16)(v.z*s); r[7]=(_Float16)(v.w*s);
    return r;
}

// ---------------------------------------------------------------------------
// K1: MFMA 2-layer LSTM — R2/R6 structure (proven 119.5us, VGPR 64, no
// spill). Unified VGPR+AGPR (~128/wave) hard-caps occupancy at 4 waves/SIMD.
// R9 delta: per-gate exp2-domain scale folded into f16 weights/bias
// (sc = -log2e for i,f,o; -2log2e for g). NOTE: bias-as-MFMA-C rejected —
// the 16-VGPR bv[4] splat would breach the 128-unified cap (R3/R4 cliff).
// ---------------------------------------------------------------------------
#define SXW (TT * 8 + 8)

__global__ __launch_bounds__(512, 4)
void lstm_fused_kernel(const float* __restrict__ x,
                       const float* __restrict__ Wih0, const float* __restrict__ Whh0,
                       const float* __restrict__ bih0, const float* __restrict__ bhh0,
                       const float* __restrict__ Wih1, const float* __restrict__ Whh1,
                       const float* __restrict__ bih1, const float* __restrict__ bhh1,
                       const float* __restrict__ Wt, const float* __restrict__ bt,
                       const float* __restrict__ av,
                       float* __restrict__ last_out,
                       float* __restrict__ s1g, float* __restrict__ s2g)
{
    __shared__ _Float16 sxp[16][SXW];
    __shared__ _Float16 h0buf[2][16][72];
    __shared__ _Float16 h1buf[2][16][72];
    __shared__ _Float16 zero16[8];
    __shared__ float sv1[HH], sv2[HH], sc12[2];

    const int tid  = threadIdx.x;
    const int w    = tid >> 6;
    const int grp  = w >> 2;
    const int cg   = w & 3;
    const int lane = tid & 63;
    const int quad = lane >> 4;
    const int l15  = lane & 15;
    const int hc   = cg * 16 + l15;
    const int n0   = blockIdx.x * 16;

    for (int i = tid; i < 16 * SXW / 2; i += 512) ((unsigned*)sxp)[i] = 0u;
    for (int i = tid; i < 2 * 16 * 72 / 2; i += 512) ((unsigned*)h0buf)[i] = 0u;
    for (int i = tid; i < 2 * 16 * 72 / 2; i += 512) ((unsigned*)h1buf)[i] = 0u;
    if (tid < 4) ((unsigned*)zero16)[tid] = 0u;
    __syncthreads();

    for (int idx = tid; idx < 16 * TT * DF; idx += 512) {
        const int m = idx / (TT * DF);
        const int r = idx - m * (TT * DF);
        const int t = r / DF;
        const int d = r - t * DF;
        sxp[m][t * 8 + d] = (_Float16)x[(size_t)(n0 + m) * (TT * DF) + r];
    }

    // GAT-prep small vectors (redundant per block, overlaps with weight loads)
    if (tid < HH) {
        float a1 = 0.f, a2 = 0.f;
        #pragma unroll 8
        for (int h = 0; h < HH; h++) {
            const float wt = Wt[h * HH + tid];
            a1 += wt * av[h];
            a2 += wt * av[HH + h];
        }
        sv1[tid] = a1; sv2[tid] = a2;
    } else if (tid == 64 || tid == 65) {
        const float* ap = av + (tid - 64) * HH;
        float c = 0.f;
        #pragma unroll 8
        for (int h = 0; h < HH; h++) c += bt[h] * ap[h];
        sc12[tid - 64] = c;
    }

    half8 wA[4][2], wB[4][2];
    float bias[4];
    half8 hzero;
    #pragma unroll
    for (int j = 0; j < 8; j++) hzero[j] = (_Float16)0.f;

    if (grp == 0) {
        #pragma unroll
        for (int nt = 0; nt < 4; nt++) {
            const float sc = (nt == 2) ? (-2.f * LOG2E) : (-LOG2E);
            const int g = nt * 64 + hc;
            wA[nt][0] = ldw8s(Whh0 + (size_t)g * HH + quad * 8, sc);
            wA[nt][1] = ldw8s(Whh0 + (size_t)g * HH + 32 + quad * 8, sc);
            bias[nt]  = (bih0[g] + bhh0[g]) * sc;
            half8 t = hzero;
            if (quad == 0) {
                #pragma unroll
                for (int j = 0; j < DF; j++) t[j] = (_Float16)(Wih0[g * DF + j] * sc);
            }
            wB[nt][0] = t;
            wB[nt][1] = hzero;
        }
    } else {
        #pragma unroll
        for (int nt = 0; nt < 4; nt++) {
            const float sc = (nt == 2) ? (-2.f * LOG2E) : (-LOG2E);
            const int g = nt * 64 + hc;
            wA[nt][0] = ldw8s(Wih1 + (size_t)g * HH + quad * 8, sc);
            wA[nt][1] = ldw8s(Wih1 + (size_t)g * HH + 32 + quad * 8, sc);
            wB[nt][0] = ldw8s(Whh1 + (size_t)g * HH + quad * 8, sc);
            wB[nt][1] = ldw8s(Whh1 + (size_t)g * HH + 32 + quad * 8, sc);
            bias[nt]  = (bih1[g] + bhh1[g]) * sc;
        }
    }

    float cs[4] = {0.f, 0.f, 0.f, 0.f};
    __syncthreads();

    for (int i = 0; i <= TT; i++) {
        const int p = i & 1;
        if (grp == 0) {
            if (i < TT) {
                const half8 a0 = *(const half8*)&h0buf[p][l15][quad * 8];
                const half8 a1 = *(const half8*)&h0buf[p][l15][32 + quad * 8];
                const _Float16* xap = (quad == 0) ? &sxp[l15][i * 8] : zero16;
                const half8 ax = *(const half8*)xap;
                f32x4 gv[4];
                #pragma unroll
                for (int nt = 0; nt < 4; nt++) {
                    f32x4 c; c[0] = bias[nt]; c[1] = bias[nt]; c[2] = bias[nt]; c[3] = bias[nt];
                    c = MFMA16(ax, wB[nt][0], c);
                    c = MFMA16(a0, wA[nt][0], c);
                    c = MFMA16(a1, wA[nt][1], c);
                    gv[nt] = c;
                }
                _Float16 (*h0w)[72] = h0buf[p ^ 1];
                #pragma unroll
                for (int reg = 0; reg < 4; reg++) {
                    const float hv = lstm_act2s(gv[0][reg], gv[1][reg], gv[2][reg], gv[3][reg], cs[reg]);
                    h0w[quad * 4 + reg][hc] = (_Float16)hv;
                }
            }
        } else {
            if (i > 0) {
                const half8 a00 = *(const half8*)&h0buf[p][l15][quad * 8];
                const half8 a01 = *(const half8*)&h0buf[p][l15][32 + quad * 8];
                const half8 a10 = *(const half8*)&h1buf[p][l15][quad * 8];
                const half8 a11 = *(const half8*)&h1buf[p][l15][32 + quad * 8];
                f32x4 gv[4];
                #pragma unroll
                for (int nt = 0; nt < 4; nt++) {
                    f32x4 c; c[0] = bias[nt]; c[1] = bias[nt]; c[2] = bias[nt]; c[3] = bias[nt];
                    c = MFMA16(a00, wA[nt][0], c);
                    c = MFMA16(a01, wA[nt][1], c);
                    c = MFMA16(a10, wB[nt][0], c);
                    c = MFMA16(a11, wB[nt][1], c);
                    gv[nt] = c;
                }
                _Float16 (*h1w)[72] = h1buf[p ^ 1];
                #pragma unroll
                for (int reg = 0; reg < 4; reg++) {
                    const float hv = lstm_act2s(gv[0][reg], gv[1][reg], gv[2][reg], gv[3][reg], cs[reg]);
                    h1w[quad * 4 + reg][hc] = (_Float16)hv;
                    if (i == TT) last_out[(size_t)(n0 + quad * 4 + reg) * HH + hc] = hv;
                }
            }
        }
        __syncthreads();
    }

    // ---- epilogue: s1/s2 from final h1 (in h1buf[1]; TT=60 even) ----
    {
        const _Float16 (*hf)[72] = h1buf[1];
        const int r  = tid >> 5;
        const int c0 = tid & 31;
        const float h1a = (float)hf[r][c0];
        const float h1b = (float)hf[r][c0 + 32];
        float p1 = h1a * sv1[c0] + h1b * sv1[c0 + 32];
        float p2 = h1a * sv2[c0] + h1b * sv2[c0 + 32];
        #pragma unroll
        for (int off = 16; off > 0; off >>= 1) {
            p1 += __shfl_xor(p1, off);
            p2 += __shfl_xor(p2, off);
        }
        if (c0 == 0) {
            s1g[n0 + r] = p1 + sc12[0];
            s2g[n0 + r] = p2 + sc12[1];
        }
    }
}

// ---------------------------------------------------------------------------
// K2: rank + factors (R8 structure: 1024 thr, float4 staging + rank loop).
// ---------------------------------------------------------------------------
__global__ __launch_bounds__(1024)
void rankfac_kernel(const float* __restrict__ s1g, const float* __restrict__ s2g,
                    float* __restrict__ Z, float* __restrict__ Ai, float* __restrict__ Bi,
                    float* __restrict__ U, float* __restrict__ W,
                    int* __restrict__ iperm, float* __restrict__ sortedD)
{
    __shared__ float sb[NN];      // 32 KB
    __shared__ float sredw[16];
    __shared__ int   sRank[32];
    const int tid  = threadIdx.x;
    const int lane = tid & 63;
    const int wv   = tid >> 6;
    const int b    = blockIdx.x;
    const int j0   = b * 32;

    {
        const float4* g4 = (const float4*)s1g;
        float4* s4 = (float4*)sb;
        for (int idx = tid; idx < NN / 4; idx += 1024) s4[idx] = g4[idx];
    }
    if (tid < 32) sRank[tid] = 0;
    __syncthreads();

    // block max (deterministic & identical across blocks: same data, same order)
    float m = -1e30f;
    for (int idx = tid; idx < NN; idx += 1024) m = fmaxf(m, sb[idx]);
    #pragma unroll
    for (int off = 32; off > 0; off >>= 1) m = fmaxf(m, __shfl_xor(m, off));
    if (lane == 0) sredw[wv] = m;
    __syncthreads();
    if (tid == 0) {
        float mm = sredw[0];
        #pragma unroll
        for (int q = 1; q < 16; q++) mm = fmaxf(mm, sredw[q]);
        sredw[0] = mm;
    }
    __syncthreads();
    const float s1max = sredw[0];

    if (tid < 32) {
        const int j = j0 + tid;
        const float z  = s2g[j] + s1max;
        const float mi = lrelu_(z);
        Z[j]  = z;
        Ai[j] = __expf(z - mi);
        Bi[j] = __expf(0.01f * z - mi);
        const float d = sb[j] - s1max;
        U[j] = __expf(d);
        W[j] = __expf(0.01f * d);
    }
    {
        const int jl = tid & 31;
        const int part = tid >> 5;          // 0..31
        const float sj = sb[j0 + jl];
        const int jg = j0 + jl;
        const int k0 = part * (NN / 32);    // 256 elems per part
        const float4* sb4 = (const float4*)&sb[k0];
        int cnt = 0;
        #pragma unroll 8
        for (int it = 0; it < NN / 32 / 4; it++) {   // 64 float4 reads
            const float4 v = sb4[it];
            const int kb = k0 + it * 4;
            cnt += (v.x < sj || (v.x == sj && kb + 0 < jg)) ? 1 : 0;
            cnt += (v.y < sj || (v.y == sj && kb + 1 < jg)) ? 1 : 0;
            cnt += (v.z < sj || (v.z == sj && kb + 2 < jg)) ? 1 : 0;
            cnt += (v.w < sj || (v.w == sj && kb + 3 < jg)) ? 1 : 0;
        }
        atomicAdd(&sRank[jl], cnt);
    }
    __syncthreads();
    if (tid < 32) {
        const int r = sRank[tid];
        iperm[r] = j0 + tid;
        sortedD[r] = sb[j0 + tid] - s1max;
    }
}

// ---------------------------------------------------------------------------
// K3: chunk column sums via iperm gather (coalesced row loads into LDS).
// ---------------------------------------------------------------------------
__global__ __launch_bounds__(256)
void scanA_kernel(const float* __restrict__ last, const float* __restrict__ U,
                  const float* __restrict__ W, const int* __restrict__ iperm,
                  float* __restrict__ chunkSum)
{
    __shared__ int   sj[CH];
    __shared__ float su[CH], sw[CH];
    __shared__ float al[CH][HH], bl[CH][HH];
    const int tid = threadIdx.x;
    const int b   = blockIdx.x;
    if (tid < CH) {
        const int j = iperm[b * CH + tid];
        sj[tid] = j; su[tid] = U[j]; sw[tid] = W[j];
    }
    __syncthreads();
    for (int idx = tid; idx < CH * HH; idx += 256) {
        const int rr = idx >> 6, c = idx & 63;
        const float lv = last[(size_t)sj[rr] * HH + c];
        al[rr][c] = su[rr] * lv;
        bl[rr][c] = sw[rr] * lv;
    }
    __syncthreads();
    if (tid < 130) {
        const int c = tid;
        float s = 0.f;
        if (c < 64) {
            for (int rr = 0; rr < CH; rr++) s += al[rr][c];
        } else if (c < 128) {
            for (int rr = 0; rr < CH; rr++) s += bl[rr][c - 64];
        } else if (c == 128) {
            for (int rr = 0; rr < CH; rr++) s += su[rr];
        } else {
            for (int rr = 0; rr < CH; rr++) s += sw[rr];
        }
        chunkSum[b * RS + c] = s;
    }
}

// ---------------------------------------------------------------------------
// K4: PP fill with SEGMENTED chunk prefix (R8 structure).
// ---------------------------------------------------------------------------
__global__ __launch_bounds__(1024)
void scanC_kernel(const float* __restrict__ last, const float* __restrict__ U,
                  const float* __restrict__ W, const int* __restrict__ iperm,
                  const float* __restrict__ chunkSum, float* __restrict__ PP)
{
    __shared__ int   sj[CH];
    __shared__ float su[CH], sw[CH];
    __shared__ float al[CH][HH], bl[CH][HH];
    __shared__ float pref[130][4];
    const int tid = threadIdx.x;
    const int b   = blockIdx.x;
    if (tid < CH) {
        const int j = iperm[b * CH + tid];
        sj[tid] = j; su[tid] = U[j]; sw[tid] = W[j];
    }
    __syncthreads();
    for (int idx = tid; idx < CH * HH; idx += 1024) {
        const int rr = idx >> 6, c = idx & 63;
        const float lv = last[(size_t)sj[rr] * HH + c];
        al[rr][c] = su[rr] * lv;
        bl[rr][c] = sw[rr] * lv;
    }
    // segmented predicated prefix partials (independent of the gather above)
    {
        const int c   = tid >> 2;     // 0..255
        const int seg = tid & 3;
        if (c < 130) {
            const bool rev = (c < 64) || (c == 128);
            const int k0 = seg * (NB / 4);
            float s = 0.f;
            #pragma unroll 8
            for (int k = k0; k < k0 + NB / 4; k++) {
                const bool take = rev ? (k > b) : (k < b);
                s += take ? chunkSum[k * RS + c] : 0.f;
            }
            pref[c][seg] = s;
        }
    }
    __syncthreads();
    if (tid < 130) {
        const int c = tid;
        const bool rev = (c < 64) || (c == 128);
        float run = (pref[c][0] + pref[c][1]) + (pref[c][2] + pref[c][3]);
        if (rev) {
            if (b == NB - 1) PP[(size_t)NN * RS + c] = 0.f;
            for (int rr = CH - 1; rr >= 0; rr--) {
                const float val = (c < 64) ? al[rr][c] : su[rr];
                run += val;
                PP[(size_t)(b * CH + rr) * RS + c] = run;
            }
        } else {
            for (int rr = 0; rr < CH; rr++) {
                PP[(size_t)(b * CH + rr) * RS + c] = run;
                run += (c < 128) ? bl[rr][c - 64] : sw[rr];
            }
            if (b == NB - 1) PP[(size_t)NN * RS + c] = run;
        }
    }
}

// ---------------------------------------------------------------------------
// K5: apply + FC head. R9: binary search runs on GLOBAL sortedD (L2-resident,
// 32 outstanding searches/CU hide the 13 probes) — drops the 32KB sdD staging
// (16MB of L2 reads across 512 blocks) and its barrier.
// ---------------------------------------------------------------------------
__global__ __launch_bounds__(256)
void applyfc_kernel(const float* __restrict__ last,
                    const float* __restrict__ Z, const float* __restrict__ Ai, const float* __restrict__ Bi,
                    const float* __restrict__ sortedD, const float* __restrict__ PP,
                    const float* __restrict__ Wfc, const float* __restrict__ bfc,
                    const float* __restrict__ Wout, const float* __restrict__ bout,
                    float* __restrict__ out)
{
    __shared__ float sW[HH][HH + 1];
    __shared__ float sbF[HH], saF[HH];
    const int tid = threadIdx.x;
    for (int idx = tid; idx < HH * HH; idx += 256) {
        const int h = idx >> 6, d = idx & 63;
        sW[d][h] = Wfc[idx];
    }
    if (tid < HH) { sbF[tid] = bfc[tid]; saF[tid] = Wout[tid]; }
    __syncthreads();

    const int wv = tid >> 6, lane = tid & 63;
    const int i0 = blockIdx.x * 16 + wv * 4;
    float zi[4]; int lo[4], hi[4];
    #pragma unroll
    for (int q = 0; q < 4; q++) { zi[q] = Z[i0 + q]; lo[q] = 0; hi[q] = NN; }
    for (int iter = 0; iter < 13; iter++) {
        #pragma unroll
        for (int q = 0; q < 4; q++) {
            if (lo[q] < hi[q]) {
                const int mid = (lo[q] + hi[q]) >> 1;
                const float dm = sortedD[mid];
                if (zi[q] + dm > 0.f) hi[q] = mid; else lo[q] = mid + 1;
            }
        }
    }
    float gv[4];
    #pragma unroll
    for (int q = 0; q < 4; q++) {
        const int i = i0 + q;
        const float* rowp = PP + (size_t)lo[q] * RS;
        const float pu  = rowp[lane];
        const float pw  = rowp[64 + lane];
        const float pud = rowp[128];
        const float pwd = rowp[129];
        const float ai = Ai[i], bi = Bi[i];
        const float numer = bi * pw + ai * pu;
        const float den   = bi * pwd + ai * pud;
        const float lv = last[(size_t)i * HH + lane];
        gv[q] = numer * __builtin_amdgcn_rcpf(den) + lv;
    }
    const float bo = bout[0];
    #pragma unroll
    for (int q = 0; q < 4; q++) {
        float acc = sbF[lane];
        #pragma unroll
        for (int d = 0; d < HH; d++) acc += __shfl(gv[q], d) * sW[d][lane];
        float prod = lrelu_(acc) * saF[lane];
        #pragma unroll
        for (int off = 32; off > 0; off >>= 1) prod += __shfl_xor(prod, off);
        if (lane == 0) out[i0 + q] = prod + bo;
    }
}

extern "C" void kernel_launch(void* const* d_in, const int* in_sizes, int n_in,
                              void* d_out, int out_size, void* d_ws, size_t ws_size,
                              hipStream_t stream)
{
    (void)in_sizes; (void)n_in; (void)out_size; (void)ws_size;
    const float* x    = (const float*)d_in[0];
    const float* Wih0 = (const float*)d_in[1];
    const float* Whh0 = (const float*)d_in[2];
    const float* bih0 = (const float*)d_in[3];
    const float* bhh0 = (const float*)d_in[4];
    const float* Wih1 = (const float*)d_in[5];
    const float* Whh1 = (const float*)d_in[6];
    const float* bih1 = (const float*)d_in[7];
    const float* bhh1 = (const float*)d_in[8];
    const float* Wt   = (const float*)d_in[9];
    const float* bt   = (const float*)d_in[10];
    const float* a    = (const float*)d_in[11];
    const float* Wfc  = (const float*)d_in[12];
    const float* bfc  = (const float*)d_in[13];
    const float* Wout = (const float*)d_in[14];
    const float* bout = (const float*)d_in[15];
    float* out = (float*)d_out;

    float* ws       = (float*)d_ws;
    float* last     = ws;                           // N*H
    float* s1g      = last + (size_t)NN*HH;         // N
    float* s2g      = s1g + NN;                     // N
    float* Z        = s2g + NN;                     // N
    float* Ai       = Z + NN;                       // N
    float* Bi       = Ai + NN;                      // N
    float* U        = Bi + NN;                      // N
    float* W        = U + NN;                       // N
    float* sortedD  = W + NN;                       // N
    int*   iperm    = (int*)(sortedD + NN);         // N ints
    float* chunkSum = (float*)(iperm + NN);         // NB*RS
    float* chunkOfs = chunkSum + NB*RS;             // NB*RS (unused; layout kept)
    float* PP       = chunkOfs + NB*RS;             // (N+1)*RS

    lstm_fused_kernel<<<dim3(NN / 16), dim3(512), 0, stream>>>(
        x, Wih0, Whh0, bih0, bhh0, Wih1, Whh1, bih1, bhh1,
        Wt, bt, a, last, s1g, s2g);
    rankfac_kernel<<<dim3(NB), dim3(1024), 0, stream>>>(
        s1g, s2g, Z, Ai, Bi, U, W, iperm, sortedD);
    scanA_kernel<<<dim3(NB), dim3(256), 0, stream>>>(last, U, W, iperm, chunkSum);
    scanC_kernel<<<dim3(NB), dim3(1024), 0, stream>>>(last, U, W, iperm, chunkSum, PP);
    applyfc_kernel<<<dim3(NN / 16), dim3(256), 0, stream>>>(
        last, Z, Ai, Bi, sortedD, PP, Wfc, bfc, Wout, bout, out);
}

// Round 11
// 234.588 us; speedup vs baseline: 1.0127x; 1.0127x over previous
//
#include <hip/hip_runtime.h>

#define NN 8192
#define TT 60
#define DF 6
#define HH 64
#define GG 256   // 4*H
#define RS 132   // payload width: [0..63] u*last, [64..127] w*last, [128] u, [129] w
#define CH 32    // ranks per chunk/block
#define NB 256   // chunks

typedef _Float16 half8 __attribute__((ext_vector_type(8)));
typedef float f32x4 __attribute__((ext_vector_type(4)));
#define MFMA16(a, b, c) __builtin_amdgcn_mfma_f32_16x16x32_f16((a), (b), (c), 0, 0, 0)

#define LOG2E 1.44269504f

__device__ __forceinline__ float lrelu_(float x) { return x > 0.0f ? x : 0.01f * x; }

// Fused LSTM activations, exp2-domain inputs: gate pre-activations arrive
// ALREADY scaled by -log2e (i,f,o) / -2log2e (g) — folded into the f16
// weights+biases at load (R10: K1 119.4->118.2, VALUBusy 58->54%).
// 5 exp + 3 rcp; clamp only tanh-type args at 63 (saturation exact).
__device__ __forceinline__ float lstm_act2s(float gi, float gf, float gg, float go,
                                            float& c)
{
    const float ei = __builtin_amdgcn_exp2f(gi);
    const float ef = __builtin_amdgcn_exp2f(gf);
    const float eg = __builtin_amdgcn_exp2f(fminf(gg, 63.f));
    const float sf = __builtin_amdgcn_rcpf(1.f + ef);
    const float tg_si = (1.f - eg) * __builtin_amdgcn_rcpf((1.f + ei) * (1.f + eg));
    c = __builtin_fmaf(sf, c, tg_si);
    const float eo = __builtin_amdgcn_exp2f(go);
    const float ec = __builtin_amdgcn_exp2f(fminf(c * (-2.f * LOG2E), 63.f));
    return (1.f - ec) * __builtin_amdgcn_rcpf((1.f + eo) * (1.f + ec));
}

__device__ __forceinline__ half8 ldw8s(const float* __restrict__ p, float s) {
    const float4* q = (const float4*)p;
    float4 u = q[0], v = q[1];
    half8 r;
    r[0]=(_Float16)(u.x*s); r[1]=(_Float16)(u.y*s); r[2]=(_Float16)(u.z*s); r[3]=(_Float16)(u.w*s);
    r[4]=(_Float16)(v.x*s); r[5]=(_Float16)(v.y*s); r[6]=(_Float16)(v.z*s); r[7]=(_Float16)(v.w*s);
    return r;
}

// ---------------------------------------------------------------------------
// K1: MFMA 2-layer LSTM — R2/R6 structure + R9/R10 exp2-domain weight fold
// (measured 118.2-118.8us, VGPR 64, no spill). Unified VGPR+AGPR (~128/wave)
// hard-caps occupancy at 4 waves/SIMD; remaining ~46% stall is chain latency
// (structural floor — R10 confirmed issue-count cuts no longer convert).
// ---------------------------------------------------------------------------
#define SXW (TT * 8 + 8)

__global__ __launch_bounds__(512, 4)
void lstm_fused_kernel(const float* __restrict__ x,
                       const float* __restrict__ Wih0, const float* __restrict__ Whh0,
                       const float* __restrict__ bih0, const float* __restrict__ bhh0,
                       const float* __restrict__ Wih1, const float* __restrict__ Whh1,
                       const float* __restrict__ bih1, const float* __restrict__ bhh1,
                       const float* __restrict__ Wt, const float* __restrict__ bt,
                       const float* __restrict__ av,
                       float* __restrict__ last_out,
                       float* __restrict__ s1g, float* __restrict__ s2g)
{
    __shared__ _Float16 sxp[16][SXW];
    __shared__ _Float16 h0buf[2][16][72];
    __shared__ _Float16 h1buf[2][16][72];
    __shared__ _Float16 zero16[8];
    __shared__ float sv1[HH], sv2[HH], sc12[2];

    const int tid  = threadIdx.x;
    const int w    = tid >> 6;
    const int grp  = w >> 2;
    const int cg   = w & 3;
    const int lane = tid & 63;
    const int quad = lane >> 4;
    const int l15  = lane & 15;
    const int hc   = cg * 16 + l15;
    const int n0   = blockIdx.x * 16;

    for (int i = tid; i < 16 * SXW / 2; i += 512) ((unsigned*)sxp)[i] = 0u;
    for (int i = tid; i < 2 * 16 * 72 / 2; i += 512) ((unsigned*)h0buf)[i] = 0u;
    for (int i = tid; i < 2 * 16 * 72 / 2; i += 512) ((unsigned*)h1buf)[i] = 0u;
    if (tid < 4) ((unsigned*)zero16)[tid] = 0u;
    __syncthreads();

    for (int idx = tid; idx < 16 * TT * DF; idx += 512) {
        const int m = idx / (TT * DF);
        const int r = idx - m * (TT * DF);
        const int t = r / DF;
        const int d = r - t * DF;
        sxp[m][t * 8 + d] = (_Float16)x[(size_t)(n0 + m) * (TT * DF) + r];
    }

    // GAT-prep small vectors (redundant per block, overlaps with weight loads)
    if (tid < HH) {
        float a1 = 0.f, a2 = 0.f;
        #pragma unroll 8
        for (int h = 0; h < HH; h++) {
            const float wt = Wt[h * HH + tid];
            a1 += wt * av[h];
            a2 += wt * av[HH + h];
        }
        sv1[tid] = a1; sv2[tid] = a2;
    } else if (tid == 64 || tid == 65) {
        const float* ap = av + (tid - 64) * HH;
        float c = 0.f;
        #pragma unroll 8
        for (int h = 0; h < HH; h++) c += bt[h] * ap[h];
        sc12[tid - 64] = c;
    }

    half8 wA[4][2], wB[4][2];
    float bias[4];
    half8 hzero;
    #pragma unroll
    for (int j = 0; j < 8; j++) hzero[j] = (_Float16)0.f;

    if (grp == 0) {
        #pragma unroll
        for (int nt = 0; nt < 4; nt++) {
            const float sc = (nt == 2) ? (-2.f * LOG2E) : (-LOG2E);
            const int g = nt * 64 + hc;
            wA[nt][0] = ldw8s(Whh0 + (size_t)g * HH + quad * 8, sc);
            wA[nt][1] = ldw8s(Whh0 + (size_t)g * HH + 32 + quad * 8, sc);
            bias[nt]  = (bih0[g] + bhh0[g]) * sc;
            half8 t = hzero;
            if (quad == 0) {
                #pragma unroll
                for (int j = 0; j < DF; j++) t[j] = (_Float16)(Wih0[g * DF + j] * sc);
            }
            wB[nt][0] = t;
            wB[nt][1] = hzero;
        }
    } else {
        #pragma unroll
        for (int nt = 0; nt < 4; nt++) {
            const float sc = (nt == 2) ? (-2.f * LOG2E) : (-LOG2E);
            const int g = nt * 64 + hc;
            wA[nt][0] = ldw8s(Wih1 + (size_t)g * HH + quad * 8, sc);
            wA[nt][1] = ldw8s(Wih1 + (size_t)g * HH + 32 + quad * 8, sc);
            wB[nt][0] = ldw8s(Whh1 + (size_t)g * HH + quad * 8, sc);
            wB[nt][1] = ldw8s(Whh1 + (size_t)g * HH + 32 + quad * 8, sc);
            bias[nt]  = (bih1[g] + bhh1[g]) * sc;
        }
    }

    float cs[4] = {0.f, 0.f, 0.f, 0.f};
    __syncthreads();

    for (int i = 0; i <= TT; i++) {
        const int p = i & 1;
        if (grp == 0) {
            if (i < TT) {
                const half8 a0 = *(const half8*)&h0buf[p][l15][quad * 8];
                const half8 a1 = *(const half8*)&h0buf[p][l15][32 + quad * 8];
                const _Float16* xap = (quad == 0) ? &sxp[l15][i * 8] : zero16;
                const half8 ax = *(const half8*)xap;
                f32x4 gv[4];
                #pragma unroll
                for (int nt = 0; nt < 4; nt++) {
                    f32x4 c; c[0] = bias[nt]; c[1] = bias[nt]; c[2] = bias[nt]; c[3] = bias[nt];
                    c = MFMA16(ax, wB[nt][0], c);
                    c = MFMA16(a0, wA[nt][0], c);
                    c = MFMA16(a1, wA[nt][1], c);
                    gv[nt] = c;
                }
                _Float16 (*h0w)[72] = h0buf[p ^ 1];
                #pragma unroll
                for (int reg = 0; reg < 4; reg++) {
                    const float hv = lstm_act2s(gv[0][reg], gv[1][reg], gv[2][reg], gv[3][reg], cs[reg]);
                    h0w[quad * 4 + reg][hc] = (_Float16)hv;
                }
            }
        } else {
            if (i > 0) {
                const half8 a00 = *(const half8*)&h0buf[p][l15][quad * 8];
                const half8 a01 = *(const half8*)&h0buf[p][l15][32 + quad * 8];
                const half8 a10 = *(const half8*)&h1buf[p][l15][quad * 8];
                const half8 a11 = *(const half8*)&h1buf[p][l15][32 + quad * 8];
                f32x4 gv[4];
                #pragma unroll
                for (int nt = 0; nt < 4; nt++) {
                    f32x4 c; c[0] = bias[nt]; c[1] = bias[nt]; c[2] = bias[nt]; c[3] = bias[nt];
                    c = MFMA16(a00, wA[nt][0], c);
                    c = MFMA16(a01, wA[nt][1], c);
                    c = MFMA16(a10, wB[nt][0], c);
                    c = MFMA16(a11, wB[nt][1], c);
                    gv[nt] = c;
                }
                _Float16 (*h1w)[72] = h1buf[p ^ 1];
                #pragma unroll
                for (int reg = 0; reg < 4; reg++) {
                    const float hv = lstm_act2s(gv[0][reg], gv[1][reg], gv[2][reg], gv[3][reg], cs[reg]);
                    h1w[quad * 4 + reg][hc] = (_Float16)hv;
                    if (i == TT) last_out[(size_t)(n0 + quad * 4 + reg) * HH + hc] = hv;
                }
            }
        }
        __syncthreads();
    }

    // ---- epilogue: s1/s2 from final h1 (in h1buf[1]; TT=60 even) ----
    {
        const _Float16 (*hf)[72] = h1buf[1];
        const int r  = tid >> 5;
        const int c0 = tid & 31;
        const float h1a = (float)hf[r][c0];
        const float h1b = (float)hf[r][c0 + 32];
        float p1 = h1a * sv1[c0] + h1b * sv1[c0 + 32];
        float p2 = h1a * sv2[c0] + h1b * sv2[c0 + 32];
        #pragma unroll
        for (int off = 16; off > 0; off >>= 1) {
            p1 += __shfl_xor(p1, off);
            p2 += __shfl_xor(p2, off);
        }
        if (c0 == 0) {
            s1g[n0 + r] = p1 + sc12[0];
            s2g[n0 + r] = p2 + sc12[1];
        }
    }
}

// ---------------------------------------------------------------------------
// K2: rank + factors (R8 structure: 1024 thr, float4 staging + rank loop).
// ---------------------------------------------------------------------------
__global__ __launch_bounds__(1024)
void rankfac_kernel(const float* __restrict__ s1g, const float* __restrict__ s2g,
                    float* __restrict__ Z, float* __restrict__ Ai, float* __restrict__ Bi,
                    float* __restrict__ U, float* __restrict__ W,
                    int* __restrict__ iperm, float* __restrict__ sortedD)
{
    __shared__ float sb[NN];      // 32 KB
    __shared__ float sredw[16];
    __shared__ int   sRank[32];
    const int tid  = threadIdx.x;
    const int lane = tid & 63;
    const int wv   = tid >> 6;
    const int b    = blockIdx.x;
    const int j0   = b * 32;

    {
        const float4* g4 = (const float4*)s1g;
        float4* s4 = (float4*)sb;
        for (int idx = tid; idx < NN / 4; idx += 1024) s4[idx] = g4[idx];
    }
    if (tid < 32) sRank[tid] = 0;
    __syncthreads();

    // block max (deterministic & identical across blocks: same data, same order)
    float m = -1e30f;
    for (int idx = tid; idx < NN; idx += 1024) m = fmaxf(m, sb[idx]);
    #pragma unroll
    for (int off = 32; off > 0; off >>= 1) m = fmaxf(m, __shfl_xor(m, off));
    if (lane == 0) sredw[wv] = m;
    __syncthreads();
    if (tid == 0) {
        float mm = sredw[0];
        #pragma unroll
        for (int q = 1; q < 16; q++) mm = fmaxf(mm, sredw[q]);
        sredw[0] = mm;
    }
    __syncthreads();
    const float s1max = sredw[0];

    if (tid < 32) {
        const int j = j0 + tid;
        const float z  = s2g[j] + s1max;
        const float mi = lrelu_(z);
        Z[j]  = z;
        Ai[j] = __expf(z - mi);
        Bi[j] = __expf(0.01f * z - mi);
        const float d = sb[j] - s1max;
        U[j] = __expf(d);
        W[j] = __expf(0.01f * d);
    }
    {
        const int jl = tid & 31;
        const int part = tid >> 5;          // 0..31
        const float sj = sb[j0 + jl];
        const int jg = j0 + jl;
        const int k0 = part * (NN / 32);    // 256 elems per part
        const float4* sb4 = (const float4*)&sb[k0];
        int cnt = 0;
        #pragma unroll 8
        for (int it = 0; it < NN / 32 / 4; it++) {   // 64 float4 reads
            const float4 v = sb4[it];
            const int kb = k0 + it * 4;
            cnt += (v.x < sj || (v.x == sj && kb + 0 < jg)) ? 1 : 0;
            cnt += (v.y < sj || (v.y == sj && kb + 1 < jg)) ? 1 : 0;
            cnt += (v.z < sj || (v.z == sj && kb + 2 < jg)) ? 1 : 0;
            cnt += (v.w < sj || (v.w == sj && kb + 3 < jg)) ? 1 : 0;
        }
        atomicAdd(&sRank[jl], cnt);
    }
    __syncthreads();
    if (tid < 32) {
        const int r = sRank[tid];
        iperm[r] = j0 + tid;
        sortedD[r] = sb[j0 + tid] - s1max;
    }
}

// ---------------------------------------------------------------------------
// K3: chunk column sums via iperm gather (coalesced row loads into LDS).
// ---------------------------------------------------------------------------
__global__ __launch_bounds__(256)
void scanA_kernel(const float* __restrict__ last, const float* __restrict__ U,
                  const float* __restrict__ W, const int* __restrict__ iperm,
                  float* __restrict__ chunkSum)
{
    __shared__ int   sj[CH];
    __shared__ float su[CH], sw[CH];
    __shared__ float al[CH][HH], bl[CH][HH];
    const int tid = threadIdx.x;
    const int b   = blockIdx.x;
    if (tid < CH) {
        const int j = iperm[b * CH + tid];
        sj[tid] = j; su[tid] = U[j]; sw[tid] = W[j];
    }
    __syncthreads();
    for (int idx = tid; idx < CH * HH; idx += 256) {
        const int rr = idx >> 6, c = idx & 63;
        const float lv = last[(size_t)sj[rr] * HH + c];
        al[rr][c] = su[rr] * lv;
        bl[rr][c] = sw[rr] * lv;
    }
    __syncthreads();
    if (tid < 130) {
        const int c = tid;
        float s = 0.f;
        if (c < 64) {
            for (int rr = 0; rr < CH; rr++) s += al[rr][c];
        } else if (c < 128) {
            for (int rr = 0; rr < CH; rr++) s += bl[rr][c - 64];
        } else if (c == 128) {
            for (int rr = 0; rr < CH; rr++) s += su[rr];
        } else {
            for (int rr = 0; rr < CH; rr++) s += sw[rr];
        }
        chunkSum[b * RS + c] = s;
    }
}

// ---------------------------------------------------------------------------
// K4: PP fill with SEGMENTED chunk prefix (R8 structure).
// ---------------------------------------------------------------------------
__global__ __launch_bounds__(1024)
void scanC_kernel(const float* __restrict__ last, const float* __restrict__ U,
                  const float* __restrict__ W, const int* __restrict__ iperm,
                  const float* __restrict__ chunkSum, float* __restrict__ PP)
{
    __shared__ int   sj[CH];
    __shared__ float su[CH], sw[CH];
    __shared__ float al[CH][HH], bl[CH][HH];
    __shared__ float pref[130][4];
    const int tid = threadIdx.x;
    const int b   = blockIdx.x;
    if (tid < CH) {
        const int j = iperm[b * CH + tid];
        sj[tid] = j; su[tid] = U[j]; sw[tid] = W[j];
    }
    __syncthreads();
    for (int idx = tid; idx < CH * HH; idx += 1024) {
        const int rr = idx >> 6, c = idx & 63;
        const float lv = last[(size_t)sj[rr] * HH + c];
        al[rr][c] = su[rr] * lv;
        bl[rr][c] = sw[rr] * lv;
    }
    // segmented predicated prefix partials (independent of the gather above)
    {
        const int c   = tid >> 2;     // 0..255
        const int seg = tid & 3;
        if (c < 130) {
            const bool rev = (c < 64) || (c == 128);
            const int k0 = seg * (NB / 4);
            float s = 0.f;
            #pragma unroll 8
            for (int k = k0; k < k0 + NB / 4; k++) {
                const bool take = rev ? (k > b) : (k < b);
                s += take ? chunkSum[k * RS + c] : 0.f;
            }
            pref[c][seg] = s;
        }
    }
    __syncthreads();
    if (tid < 130) {
        const int c = tid;
        const bool rev = (c < 64) || (c == 128);
        float run = (pref[c][0] + pref[c][1]) + (pref[c][2] + pref[c][3]);
        if (rev) {
            if (b == NB - 1) PP[(size_t)NN * RS + c] = 0.f;
            for (int rr = CH - 1; rr >= 0; rr--) {
                const float val = (c < 64) ? al[rr][c] : su[rr];
                run += val;
                PP[(size_t)(b * CH + rr) * RS + c] = run;
            }
        } else {
            for (int rr = 0; rr < CH; rr++) {
                PP[(size_t)(b * CH + rr) * RS + c] = run;
                run += (c < 128) ? bl[rr][c - 64] : sw[rr];
            }
            if (b == NB - 1) PP[(size_t)NN * RS + c] = run;
        }
    }
}

// ---------------------------------------------------------------------------
// K5: apply + FC head — R8 version restored (R10 lesson: global binary search
// is SLOWER; the 13 probes are serial per thread so latency never hides.
// LDS sdD staging + 512 blocks x 256 thr = measured best).
// ---------------------------------------------------------------------------
__global__ __launch_bounds__(256)
void applyfc_kernel(const float* __restrict__ last,
                    const float* __restrict__ Z, const float* __restrict__ Ai, const float* __restrict__ Bi,
                    const float* __restrict__ sortedD, const float* __restrict__ PP,
                    const float* __restrict__ Wfc, const float* __restrict__ bfc,
                    const float* __restrict__ Wout, const float* __restrict__ bout,
                    float* __restrict__ out)
{
    __shared__ float sdD[NN];          // 32 KB
    __shared__ float sW[HH][HH + 1];
    __shared__ float sbF[HH], saF[HH];
    const int tid = threadIdx.x;
    {
        const float4* g4 = (const float4*)sortedD;
        float4* s4 = (float4*)sdD;
        for (int idx = tid; idx < NN / 4; idx += 256) s4[idx] = g4[idx];
    }
    for (int idx = tid; idx < HH * HH; idx += 256) {
        const int h = idx >> 6, d = idx & 63;
        sW[d][h] = Wfc[idx];
    }
    if (tid < HH) { sbF[tid] = bfc[tid]; saF[tid] = Wout[tid]; }
    __syncthreads();

    const int wv = tid >> 6, lane = tid & 63;
    const int i0 = blockIdx.x * 16 + wv * 4;
    float zi[4]; int lo[4], hi[4];
    #pragma unroll
    for (int q = 0; q < 4; q++) { zi[q] = Z[i0 + q]; lo[q] = 0; hi[q] = NN; }
    for (int iter = 0; iter < 13; iter++) {
        #pragma unroll
        for (int q = 0; q < 4; q++) {
            if (lo[q] < hi[q]) {
                const int mid = (lo[q] + hi[q]) >> 1;
                const float dm = sdD[mid];
                if (zi[q] + dm > 0.f) hi[q] = mid; else lo[q] = mid + 1;
            }
        }
    }
    float gv[4];
    #pragma unroll
    for (int q = 0; q < 4; q++) {
        const int i = i0 + q;
        const float* rowp = PP + (size_t)lo[q] * RS;
        const float pu  = rowp[lane];
        const float pw  = rowp[64 + lane];
        const float pud = rowp[128];
        const float pwd = rowp[129];
        const float ai = Ai[i], bi = Bi[i];
        const float numer = bi * pw + ai * pu;
        const float den   = bi * pwd + ai * pud;
        const float lv = last[(size_t)i * HH + lane];
        gv[q] = numer * __builtin_amdgcn_rcpf(den) + lv;
    }
    const float bo = bout[0];
    #pragma unroll
    for (int q = 0; q < 4; q++) {
        float acc = sbF[lane];
        #pragma unroll
        for (int d = 0; d < HH; d++) acc += __shfl(gv[q], d) * sW[d][lane];
        float prod = lrelu_(acc) * saF[lane];
        #pragma unroll
        for (int off = 32; off > 0; off >>= 1) prod += __shfl_xor(prod, off);
        if (lane == 0) out[i0 + q] = prod + bo;
    }
}

extern "C" void kernel_launch(void* const* d_in, const int* in_sizes, int n_in,
                              void* d_out, int out_size, void* d_ws, size_t ws_size,
                              hipStream_t stream)
{
    (void)in_sizes; (void)n_in; (void)out_size; (void)ws_size;
    const float* x    = (const float*)d_in[0];
    const float* Wih0 = (const float*)d_in[1];
    const float* Whh0 = (const float*)d_in[2];
    const float* bih0 = (const float*)d_in[3];
    const float* bhh0 = (const float*)d_in[4];
    const float* Wih1 = (const float*)d_in[5];
    const float* Whh1 = (const float*)d_in[6];
    const float* bih1 = (const float*)d_in[7];
    const float* bhh1 = (const float*)d_in[8];
    const float* Wt   = (const float*)d_in[9];
    const float* bt   = (const float*)d_in[10];
    const float* a    = (const float*)d_in[11];
    const float* Wfc  = (const float*)d_in[12];
    const float* bfc  = (const float*)d_in[13];
    const float* Wout = (const float*)d_in[14];
    const float* bout = (const float*)d_in[15];
    float* out = (float*)d_out;

    float* ws       = (float*)d_ws;
    float* last     = ws;                           // N*H
    float* s1g      = last + (size_t)NN*HH;         // N
    float* s2g      = s1g + NN;                     // N
    float* Z        = s2g + NN;                     // N
    float* Ai       = Z + NN;                       // N
    float* Bi       = Ai + NN;                      // N
    float* U        = Bi + NN;                      // N
    float* W        = U + NN;                       // N
    float* sortedD  = W + NN;                       // N
    int*   iperm    = (int*)(sortedD + NN);         // N ints
    float* chunkSum = (float*)(iperm + NN);         // NB*RS
    float* chunkOfs = chunkSum + NB*RS;             // NB*RS (unused; layout kept)
    float* PP       = chunkOfs + NB*RS;             // (N+1)*RS

    lstm_fused_kernel<<<dim3(NN / 16), dim3(512), 0, stream>>>(
        x, Wih0, Whh0, bih0, bhh0, Wih1, Whh1, bih1, bhh1,
        Wt, bt, a, last, s1g, s2g);
    rankfac_kernel<<<dim3(NB), dim3(1024), 0, stream>>>(
        s1g, s2g, Z, Ai, Bi, U, W, iperm, sortedD);
    scanA_kernel<<<dim3(NB), dim3(256), 0, stream>>>(last, U, W, iperm, chunkSum);
    scanC_kernel<<<dim3(NB), dim3(1024), 0, stream>>>(last, U, W, iperm, chunkSum, PP);
    applyfc_kernel<<<dim3(NN / 16), dim3(256), 0, stream>>>(
        last, Z, Ai, Bi, sortedD, PP, Wfc, bfc, Wout, bout, out);
}